// Round 14
// baseline (331.939 us; speedup 1.0000x reference)
//
#include <hip/hip_runtime.h>
#include <math.h>

#define B_ 16
#define L_ 4096
#define H_ 8
#define E_ 64
#define C_ 512     // H*E
#define K_ 24
#define NT 256
#define RPAD 257      // padded row stride (float2 units) for the 16x256 LDS matrix
#define PSTRIDE 2052  // partial-spectrum row stride (float2), bins 0..2048 used
#define G_ 64         // channel groups (8 ch each) per batch for fft_bc

__device__ __forceinline__ float2 cmul(float2 a, float2 b) {
    return make_float2(a.x * b.x - a.y * b.y, a.x * b.y + a.y * b.x);
}
__device__ __forceinline__ float2 cadd(float2 a, float2 b) { return make_float2(a.x + b.x, a.y + b.y); }
__device__ __forceinline__ float2 csub(float2 a, float2 b) { return make_float2(a.x - b.x, a.y - b.y); }

// barrier that orders LDS only: does NOT drain vmcnt, so in-flight
// global_load_lds / register prefetch survive across it
__device__ __forceinline__ void bar_lds() {
    asm volatile("s_waitcnt lgkmcnt(0)" ::: "memory");
    __builtin_amdgcn_s_barrier();
}

// 16-point DIF FFT, natural-order input; output: X[k] = a[br4[k]]
__device__ __forceinline__ void fft16(float2 a[16]) {
    const float r2 = 0.70710678118654752f;
    const float c1 = 0.92387953251128676f;  // cos(pi/8)
    const float s1 = 0.38268343236508977f;  // sin(pi/8)
    const float2 W16[8] = {
        make_float2(1.f, 0.f),  make_float2(c1, -s1),  make_float2(r2, -r2),  make_float2(s1, -c1),
        make_float2(0.f, -1.f), make_float2(-s1, -c1), make_float2(-r2, -r2), make_float2(-c1, -s1)};
    #pragma unroll
    for (int j = 0; j < 8; ++j) {
        float2 u = a[j], v = a[j + 8];
        a[j]     = cadd(u, v);
        a[j + 8] = cmul(csub(u, v), W16[j]);
    }
    #pragma unroll
    for (int b = 0; b < 16; b += 8)
        #pragma unroll
        for (int j = 0; j < 4; ++j) {
            float2 u = a[b + j], v = a[b + j + 4];
            a[b + j]     = cadd(u, v);
            a[b + j + 4] = cmul(csub(u, v), W16[2 * j]);
        }
    #pragma unroll
    for (int b = 0; b < 16; b += 4)
        #pragma unroll
        for (int j = 0; j < 2; ++j) {
            float2 u = a[b + j], v = a[b + j + 2];
            a[b + j]     = cadd(u, v);
            a[b + j + 2] = cmul(csub(u, v), W16[4 * j]);
        }
    #pragma unroll
    for (int b = 0; b < 16; b += 2) {
        float2 u = a[b], v = a[b + 1];
        a[b]     = cadd(u, v);
        a[b + 1] = csub(u, v);
    }
}

// ---------------- pipelined transpose + FFT phase A ----------------
// r13 post-mortem: phaseA stuck at ~130us (vs 81us BW floor), VALUBusy 19% —
// each block's serial load->barrier->compute chain exposes its load phase
// (~4 blocks/CU can't hide it). This version: persistent 4-window block with
// double-buffered global_load_lds staging + counted vmcnt (T3/T4 idiom):
// window w+1's 8 loads stay in flight across the barrier while w computes.
// LDS: 2 x (q,k) float[4096] = 64KB -> 2 blocks/CU. Staging is 16B/lane,
// linear LDS dest (wave-uniform base + lane*16), global quad XOR-swizzled by
// (row&3) (m173 pattern) so the column gather is 4-way instead of 8-way.
// z store: [c][k1*256+n2], wave = 4ch x 16n2 -> 4 full 128B lines/store.
__global__ __launch_bounds__(256) void k_phaseA(const float* __restrict__ q,
                                                const float* __restrict__ k,
                                                float2* __restrict__ z,
                                                int b0) {
    __shared__ float qbuf[2][4096];   // [buf][row*16 + quad*4 + j] (quad XOR-swizzled)
    __shared__ float kbuf[2][4096];
    const int br4[16] = {0, 8, 4, 12, 2, 10, 6, 14, 1, 9, 5, 13, 3, 11, 7, 15};
    const int tid = threadIdx.x;

    // XCD-contiguous bijective decode: gridDim.x = 128*P blocks
    int id  = blockIdx.x;
    int nb8 = gridDim.x >> 3;
    int wk  = (id & 7) * nb8 + (id >> 3);
    int bl  = wk >> 7;                // local batch 0..P-1
    int wb  = (wk >> 5) & 3;          // window block: w = wb*4 + wi
    int g   = wk & 31;                // 16-channel group (g,g+1 share lines, same XCD)
    int b   = b0 + bl;

    const size_t cbase = (size_t)b * L_ * C_ + g * 16;

    // staging lane decomposition (constant per thread)
    const int srow  = tid >> 2;       // 0..63 row-within-64-chunk
    const int squad = tid & 3;
    const int sn2l  = srow & 15;      // valid for every it (it adds multiples of 64)
    const int sqd   = squad ^ (sn2l & 3);   // XOR-swizzled global quad
    const int ldoff = ((tid >> 6) << 8);    // wave-uniform LDS float offset

    // compute-side mapping
    const int ch = tid >> 4, n2loc = tid & 15;
    const int col = (((ch >> 2) ^ (n2loc & 3)) << 2) + (ch & 3);
    const int tb  = (n2loc << 4) + col;

    #define STAGE(dbuf, w)                                                          \
        {                                                                            \
            const float* qw = q + cbase + (size_t)((w) << 4) * C_;                   \
            const float* kw = k + cbase + (size_t)((w) << 4) * C_;                   \
            _Pragma("unroll")                                                        \
            for (int it = 0; it < 4; ++it) {                                         \
                int r  = (it << 6) + srow;                                           \
                size_t gof = (size_t)(((r >> 4) << 8) + (r & 15)) * C_ + (sqd << 2); \
                float* ql = &qbuf[dbuf][(it << 10) + ldoff];                         \
                float* kl = &kbuf[dbuf][(it << 10) + ldoff];                         \
                __builtin_amdgcn_global_load_lds(                                    \
                    (const __attribute__((address_space(1))) uint32_t*)(qw + gof),   \
                    (__attribute__((address_space(3))) uint32_t*)ql, 16, 0, 0);      \
                __builtin_amdgcn_global_load_lds(                                    \
                    (const __attribute__((address_space(1))) uint32_t*)(kw + gof),   \
                    (__attribute__((address_space(3))) uint32_t*)kl, 16, 0, 0);      \
            }                                                                        \
        }

    STAGE(0, (wb << 2));              // prologue: window 0 into buf 0

    #pragma unroll
    for (int wi = 0; wi < 4; ++wi) {
        const int cur = wi & 1;
        const int w   = (wb << 2) + wi;
        if (wi < 3) STAGE(cur ^ 1, w + 1);          // next window in flight
        if (wi < 3) asm volatile("s_waitcnt vmcnt(8)" ::: "memory");   // drain cur's 8, keep next's 8
        else        asm volatile("s_waitcnt vmcnt(0)" ::: "memory");
        __builtin_amdgcn_s_barrier();               // all waves' cur stages visible

        // ---- gather + phase-A FFT ----
        float2 a[16];
        #pragma unroll
        for (int n1 = 0; n1 < 16; ++n1) {
            int ix = (n1 << 8) + tb;
            a[n1] = make_float2(qbuf[cur][ix], kbuf[cur][ix]);
        }
        fft16(a);
        // twiddle W4096^{n2*k1}: 4 independent chains stepped by W^{4*n2}
        int n2 = (w << 4) + n2loc;
        float sn, cs;
        sincospif((float)n2 / 2048.0f, &sn, &cs);
        const float2 w1 = make_float2(cs, -sn);
        const float2 w2 = cmul(w1, w1);
        const float2 w4 = cmul(w2, w2);
        float2 tws[4] = {w1, w2, cmul(w2, w1), w4};
        float2* zc = z + ((size_t)bl * C_ + (g * 16 + ch)) * L_ + n2;
        zc[0] = a[0];                  // k1 = 0
        #pragma unroll
        for (int k1 = 1; k1 < 16; ++k1) {
            int j = (k1 - 1) & 3;
            zc[(size_t)(k1 << 8)] = cmul(a[br4[k1]], tws[j]);
            tws[j] = cmul(tws[j], w4);
        }
        bar_lds();                     // LDS reads retired before re-staging this buf
    }
    #undef STAGE
}

// ---------------- FFT phases B+C + cross-spectrum accumulate (half spectrum) ----------------
// z[c][k1*256+n2] holds phase-A output (twiddled). Conjugate symmetry
// S(L-p)=conj(S(p)) -> accumulate only bins 0..2047 + Nyquist. Tail:
// contention-free partial stores part[b*64+g][p] (r11/r12: device atomics at
// >=8M lanes were the binding constraint). Next channel's z prefetched into
// dead a[] across the accumulate phase.
__global__ __launch_bounds__(256) void k_fft_bc(const float2* __restrict__ z,
                                                float2* __restrict__ part,
                                                int b0) {
    __shared__ float2 s[16 * RPAD];
    __shared__ float2 tw256[256];     // tw256[r1*16+m2] = W256^{m2*r1}
    const int br4[16] = {0, 8, 4, 12, 2, 10, 6, 14, 1, 9, 5, 13, 3, 11, 7, 15};
    int t  = threadIdx.x;
    int bl = blockIdx.y;
    int b  = b0 + bl;
    int g  = blockIdx.x;              // channel group of 8
    int c0 = g * 8;

    {
        int r1 = t >> 4, m2 = t & 15;
        float sn, cs;
        sincospif((float)(r1 * m2) / 128.0f, &sn, &cs);
        tw256[t] = make_float2(cs, -sn);
    }
    float accx[8], accy[8], accN = 0.f;
    #pragma unroll
    for (int r = 0; r < 8; ++r) { accx[r] = 0.f; accy[r] = 0.f; }

    const int rowB = t >> 4, m2B = t & 15;
    const int k1C = t & 15, r1C = t >> 4;

    // prefetch channel 0 (stays in flight across the setup barrier)
    float2 a[16];
    {
        const float2* zc0 = z + ((size_t)bl * C_ + c0) * L_;
        #pragma unroll
        for (int m1 = 0; m1 < 16; ++m1) a[m1] = zc0[(rowB << 8) + (m1 << 4) + m2B];
    }
    bar_lds();   // tw256 ready

    for (int cc = 0; cc < 8; ++cc) {
        // ---- phase B (input prefetched in a[]) ----
        fft16(a);
        #pragma unroll
        for (int r1 = 0; r1 < 16; ++r1)
            s[rowB * RPAD + (r1 << 4) + m2B] = cmul(a[br4[r1]], tw256[(r1 << 4) + m2B]);
        __syncthreads();
        // ---- phase C ----
        #pragma unroll
        for (int m2 = 0; m2 < 16; ++m2) a[m2] = s[k1C * RPAD + (r1C << 4) + m2];
        fft16(a);
        __syncthreads();
        #pragma unroll
        for (int r2 = 0; r2 < 16; ++r2)
            s[(r2 << 8) + (r1C << 4) + k1C] = a[br4[r2]];   // natural order, flat
        // ---- prefetch next channel into now-dead a[] ----
        if (cc < 7) {
            const float2* zn = z + ((size_t)bl * C_ + (c0 + cc + 1)) * L_;
            #pragma unroll
            for (int m1 = 0; m1 < 16; ++m1) a[m1] = zn[(rowB << 8) + (m1 << 4) + m2B];
        }
        bar_lds();   // LDS-ordering only; prefetch stays in flight
        // ---- unpack Z=Q+iK, accumulate Q*conj(K), bins 0..2047 + Nyquist ----
        #pragma unroll
        for (int r = 0; r < 8; ++r) {
            int p  = t + (r << 8);
            int pp = (L_ - p) & (L_ - 1);
            float2 A  = s[p];
            float2 Bv = s[pp];
            float Qr = 0.5f * (A.x + Bv.x);
            float Qi = 0.5f * (A.y - Bv.y);
            float Kr = 0.5f * (A.y + Bv.y);
            float Ki = 0.5f * (A.x - Bv.x);
            accx[r] += Qr * Kr - Qi * Ki;
            accy[r] += Qr * Ki + Qi * Kr;
        }
        accN += s[2048].x * s[2048].y;  // Nyquist: Q,K real there (LDS broadcast)
        bar_lds();   // accum reads done before next phase B overwrites s
    }
    // ---- contention-free coalesced partial stores (no atomics) ----
    float2* pb = part + (size_t)(b * G_ + g) * PSTRIDE;
    #pragma unroll
    for (int r = 0; r < 8; ++r)
        pb[t + (r << 8)] = make_float2(accx[r], accy[r]);
    if (t == 0) pb[2048] = make_float2(accN, 0.f);
}

// ---------------- partial-spectrum reduction: cross[b][p] = sum_g part[b][g][p] ----------------
__global__ __launch_bounds__(256) void k_reduce(const float2* __restrict__ part,
                                                float* __restrict__ cross) {
    __shared__ float2 acc2[128];
    int b  = blockIdx.x;
    int pt = blockIdx.y;
    int t  = threadIdx.x;
    int pi = t & 127, gh = t >> 7;
    int p  = pt * 128 + pi;
    float sx = 0.f, sy = 0.f;
    if (p <= 2048) {
        const float2* base = part + ((size_t)b * G_ + gh * 32) * PSTRIDE + p;
        #pragma unroll 4
        for (int g = 0; g < 32; ++g) {
            float2 v = base[(size_t)g * PSTRIDE];
            sx += v.x; sy += v.y;
        }
    }
    if (gh == 1) acc2[pi] = make_float2(sx, sy);
    __syncthreads();
    if (gh == 0 && p <= 2048) {
        float2 o = acc2[pi];
        ((float2*)cross)[(size_t)b * L_ + p] = make_float2(sx + o.x, sy + o.y);
    }
}

// ---------------- inverse FFT via conj-forward 3-phase radix-16 ----------------
// cross holds only bins 0..2048; upper half reconstructed via S(L-p)=conj(S(p)).
__global__ __launch_bounds__(256) void k_ifft(const float* __restrict__ cross,
                                              float* __restrict__ mv) {
    __shared__ float2 s[16 * RPAD];
    __shared__ float2 tw256[256];
    const int br4[16] = {0, 8, 4, 12, 2, 10, 6, 14, 1, 9, 5, 13, 3, 11, 7, 15};
    int t = threadIdx.x;
    int b = blockIdx.x;
    {
        int r1 = t >> 4, m2 = t & 15;
        float sn, cs;
        sincospif((float)(r1 * m2) / 128.0f, &sn, &cs);
        tw256[t] = make_float2(cs, -sn);
    }
    const float2* cr = (const float2*)cross + (size_t)b * L_;
    float2 a[16];
    #pragma unroll
    for (int n1 = 0; n1 < 16; ++n1) {
        int P = (n1 << 8) + t;
        int hi = P > 2048;
        float2 v = cr[hi ? (L_ - P) : P];
        // want a = conj(S(P)): P<=2048 -> conj(v); P>2048 -> S(P)=conj(v) -> a = v
        a[n1] = hi ? v : make_float2(v.x, -v.y);
    }
    // ---- phase A ----
    fft16(a);
    {
        float sn, cs;
        sincospif((float)t / 2048.0f, &sn, &cs);
        const float2 w1 = make_float2(cs, -sn);
        float2 tw = w1;
        s[t] = a[0];
        #pragma unroll
        for (int k1 = 1; k1 < 16; ++k1) {
            s[k1 * RPAD + t] = cmul(a[br4[k1]], tw);
            tw = cmul(tw, w1);
        }
    }
    __syncthreads();
    // ---- phase B ----
    const int rowB = t >> 4, m2B = t & 15;
    #pragma unroll
    for (int m1 = 0; m1 < 16; ++m1) a[m1] = s[rowB * RPAD + (m1 << 4) + m2B];
    fft16(a);
    #pragma unroll
    for (int r1 = 0; r1 < 16; ++r1)
        s[rowB * RPAD + (r1 << 4) + m2B] = cmul(a[br4[r1]], tw256[(r1 << 4) + m2B]);
    __syncthreads();
    // ---- phase C: write mv directly (k = r2*256 + t, coalesced) ----
    const int k1C = t & 15, r1C = t >> 4;
    #pragma unroll
    for (int m2 = 0; m2 < 16; ++m2) a[m2] = s[k1C * RPAD + (r1C << 4) + m2];
    fft16(a);
    const float scale = 1.0f / ((float)L_ * (float)C_);
    #pragma unroll
    for (int r2 = 0; r2 < 16; ++r2)
        mv[(size_t)b * L_ + (r2 << 8) + t] = a[br4[r2]].x * scale;
}

// ---------------- top-24 + per-batch softmax (register-resident, wave-shuffle) ----------------
__global__ __launch_bounds__(256) void k_topk(const float* __restrict__ mv,
                                              int* __restrict__ idx,
                                              float* __restrict__ wts) {
    __shared__ float wv[4];
    __shared__ int   wi[4];
    __shared__ int   idxL[K_];
    int tid = threadIdx.x;
    float vloc[16];
    #pragma unroll
    for (int r = 0; r < 16; ++r) {
        int tt = tid + (r << 8);
        float ssum = 0.f;
        for (int b = 0; b < B_; ++b) ssum += mv[(size_t)b * L_ + tt];
        vloc[r] = ssum;
    }
    int lane = tid & 63, w = tid >> 6;
    for (int i = 0; i < K_; ++i) {
        float best = -INFINITY; int bi = 1 << 30;
        #pragma unroll
        for (int r = 0; r < 16; ++r) {
            float v = vloc[r]; int ii = tid + (r << 8);
            if (v > best || (v == best && ii < bi)) { best = v; bi = ii; }
        }
        #pragma unroll
        for (int off = 32; off > 0; off >>= 1) {
            float ov = __shfl_down(best, off);
            int   oi = __shfl_down(bi, off);
            if (ov > best || (ov == best && oi < bi)) { best = ov; bi = oi; }
        }
        if (lane == 0) { wv[w] = best; wi[w] = bi; }
        __syncthreads();
        if (tid == 0) {
            float bb = wv[0]; int bj = wi[0];
            for (int j = 1; j < 4; ++j)
                if (wv[j] > bb || (wv[j] == bb && wi[j] < bj)) { bb = wv[j]; bj = wi[j]; }
            idxL[i] = bj; idx[i] = bj;
        }
        __syncthreads();
        int win = idxL[i];
        #pragma unroll
        for (int r = 0; r < 16; ++r)
            if (win == tid + (r << 8)) vloc[r] = -INFINITY;
    }
    if (tid < B_) {
        int b = tid;
        float ww[K_]; float wm = -INFINITY;
        for (int i = 0; i < K_; ++i) { ww[i] = mv[(size_t)b * L_ + idxL[i]]; wm = fmaxf(wm, ww[i]); }
        float ssum = 0.f;
        for (int i = 0; i < K_; ++i) { ww[i] = expf(ww[i] - wm); ssum += ww[i]; }
        float inv = 1.f / ssum;
        for (int i = 0; i < K_; ++i) wts[b * K_ + i] = ww[i] * inv;
    }
}

// ---------------- 24-tap circulant gather-sum, LDS tau-ring version ----------------
__global__ __launch_bounds__(256) void k_agg(const float* __restrict__ vals,
                                             const int* __restrict__ idx,
                                             const float* __restrict__ wts,
                                             float* __restrict__ out) {
    __shared__ float4 sv[L_];      // 64 KB ring: 2 blocks/CU
    __shared__ int   di[K_];
    __shared__ float dw[K_];
    const int tid = threadIdx.x;
    // XCD-aware bijective decode: 2048 blocks; xcd = id&7 owns work [xcd*256, xcd*256+256)
    int id = blockIdx.x;
    int wk = ((id & 7) << 8) | (id >> 3);
    int b  = wk >> 7;              // 0..15 (2 batches per XCD)
    int c0 = (wk & 127) << 2;      // channel-quad start

    if (tid < K_) { di[tid] = idx[tid]; dw[tid] = wts[b * K_ + tid]; }

    // ---- stage: 16 iters x 256 lanes x 16B, LDS dest linear (wave-uniform base + lane*16)
    const float* gbase = vals + (size_t)b * L_ * C_ + c0;
    #pragma unroll
    for (int it = 0; it < 16; ++it) {
        int tau = (it << 8) + tid;
        const float* g = gbase + (size_t)tau * C_;
        float4* l = &sv[(it << 8) + ((tid >> 6) << 6)];   // wave-uniform within each wave
        __builtin_amdgcn_global_load_lds(
            (const __attribute__((address_space(1))) uint32_t*)g,
            (__attribute__((address_space(3))) uint32_t*)l,
            16, 0, 0);
    }
    __syncthreads();   // drains vmcnt before barrier

    // taps/weights to registers (fully-unrolled static indexing)
    int   dir[K_]; float dwr[K_];
    #pragma unroll
    for (int i = 0; i < K_; ++i) { dir[i] = di[i]; dwr[i] = dw[i]; }

    float* obase = out + (size_t)b * L_ * C_ + c0;
    for (int r = 0; r < 16; ++r) {
        int tau = (r << 8) + tid;
        float4 acc = make_float4(0.f, 0.f, 0.f, 0.f);
        #pragma unroll
        for (int i = 0; i < K_; ++i) {
            float4 x = sv[(tau + dir[i]) & (L_ - 1)];
            float w = dwr[i];
            acc.x = fmaf(w, x.x, acc.x);
            acc.y = fmaf(w, x.y, acc.y);
            acc.z = fmaf(w, x.z, acc.z);
            acc.w = fmaf(w, x.w, acc.w);
        }
        *(float4*)(obase + (size_t)tau * C_) = acc;
    }
}

extern "C" void kernel_launch(void* const* d_in, const int* in_sizes, int n_in,
                              void* d_out, int out_size, void* d_ws, size_t ws_size,
                              hipStream_t stream) {
    const float* q = (const float*)d_in[0];
    const float* k = (const float*)d_in[1];
    const float* v = (const float*)d_in[2];
    float* out = (float*)d_out;
    char* ws = (char*)d_ws;

    // ws layout: [cross 512KB | mv 256KB | idx | wts | part at 2MB (16.8MB) | z at 20MB]
    float*  cross = (float*)ws;
    float*  mv    = (float*)(ws + (1 << 20));
    int*    idx   = (int*)(ws + (1 << 20) + (1 << 18));
    float*  wts   = (float*)(ws + (1 << 20) + (1 << 18) + 4096);
    float2* part  = (float2*)(ws + (2 << 20));
    float2* z     = (float2*)(ws + (size_t)(20 << 20));

    size_t zcap = (ws_size > (size_t)(20 << 20)) ? ws_size - (size_t)(20 << 20) : 0;
    int P = 16;
    while (P > 1 && (size_t)P * C_ * L_ * sizeof(float2) > zcap) P >>= 1;

    for (int b0 = 0; b0 < B_; b0 += P) {
        k_phaseA<<<128 * P, 256, 0, stream>>>(q, k, z, b0);
        dim3 g2(G_, P);
        k_fft_bc<<<g2, 256, 0, stream>>>(z, part, b0);
    }
    dim3 gr(B_, 17);
    k_reduce<<<gr, 256, 0, stream>>>(part, cross);
    k_ifft<<<B_, 256, 0, stream>>>(cross, mv);
    k_topk<<<1, 256, 0, stream>>>(mv, idx, wts);
    k_agg<<<B_ * (C_ / 4), 256, 0, stream>>>(v, idx, wts, out);
}

// Round 15
// 330.298 us; speedup vs baseline: 1.0050x; 1.0050x over previous
//
#include <hip/hip_runtime.h>
#include <math.h>

#define B_ 16
#define L_ 4096
#define H_ 8
#define E_ 64
#define C_ 512     // H*E
#define K_ 24
#define NT 256
#define RPAD 257      // padded row stride (float2 units) for the 16x256 LDS matrix
#define PSTRIDE 2052  // partial-spectrum row stride (float2), bins 0..2048 used
#define G_ 64         // channel groups (8 ch each) per batch for fft_bc

__device__ __forceinline__ float2 cmul(float2 a, float2 b) {
    return make_float2(a.x * b.x - a.y * b.y, a.x * b.y + a.y * b.x);
}
__device__ __forceinline__ float2 cadd(float2 a, float2 b) { return make_float2(a.x + b.x, a.y + b.y); }
__device__ __forceinline__ float2 csub(float2 a, float2 b) { return make_float2(a.x - b.x, a.y - b.y); }

// barrier that orders LDS only: does NOT drain vmcnt, so register prefetch
// loads stay in flight across it (no cross-thread global deps at these points)
__device__ __forceinline__ void bar_lds() {
    asm volatile("s_waitcnt lgkmcnt(0)" ::: "memory");
    __builtin_amdgcn_s_barrier();
}

// 16-point DIF FFT, natural-order input; output: X[k] = a[br4[k]]
__device__ __forceinline__ void fft16(float2 a[16]) {
    const float r2 = 0.70710678118654752f;
    const float c1 = 0.92387953251128676f;  // cos(pi/8)
    const float s1 = 0.38268343236508977f;  // sin(pi/8)
    const float2 W16[8] = {
        make_float2(1.f, 0.f),  make_float2(c1, -s1),  make_float2(r2, -r2),  make_float2(s1, -c1),
        make_float2(0.f, -1.f), make_float2(-s1, -c1), make_float2(-r2, -r2), make_float2(-c1, -s1)};
    #pragma unroll
    for (int j = 0; j < 8; ++j) {
        float2 u = a[j], v = a[j + 8];
        a[j]     = cadd(u, v);
        a[j + 8] = cmul(csub(u, v), W16[j]);
    }
    #pragma unroll
    for (int b = 0; b < 16; b += 8)
        #pragma unroll
        for (int j = 0; j < 4; ++j) {
            float2 u = a[b + j], v = a[b + j + 4];
            a[b + j]     = cadd(u, v);
            a[b + j + 4] = cmul(csub(u, v), W16[2 * j]);
        }
    #pragma unroll
    for (int b = 0; b < 16; b += 4)
        #pragma unroll
        for (int j = 0; j < 2; ++j) {
            float2 u = a[b + j], v = a[b + j + 2];
            a[b + j]     = cadd(u, v);
            a[b + j + 2] = cmul(csub(u, v), W16[4 * j]);
        }
    #pragma unroll
    for (int b = 0; b < 16; b += 2) {
        float2 u = a[b], v = a[b + 1];
        a[b]     = cadd(u, v);
        a[b + 1] = csub(u, v);
    }
}

// ---------------- fused transpose + FFT phase A (r13 version — at transpose ceiling) ----------------
// r13/r14 evidence: this version runs 3.07 TB/s = the chip's empirical
// transpose ceiling (r0 pure 64x64 transpose: 3.2 TB/s); the r14 T3/T4
// double-buffer pipeline REGRESSED it (occupancy 36->18%, conflicts x6).
// Both sides are full-line-efficient: reads are 64B segments deduped by the
// co-XCD sibling group (g,g+1); writes are 4x128B lines per wave-store.
__global__ __launch_bounds__(256) void k_phaseA(const float* __restrict__ q,
                                                const float* __restrict__ k,
                                                float2* __restrict__ z,
                                                int b0) {
    __shared__ float2 s2[256 * 17];   // [row = n1*16 + n2loc][ch], stride 17 -> 34.8 KB
    const int br4[16] = {0, 8, 4, 12, 2, 10, 6, 14, 1, 9, 5, 13, 3, 11, 7, 15};
    int w  = blockIdx.x;              // n2 window (16 of them)
    int g  = blockIdx.y;              // channel group of 16 (32 of them)
    int bl = blockIdx.z;
    int b  = b0 + bl;
    int tid = threadIdx.x;

    // ---- load 256 rows x 16 ch, float4 per (row, quad): 16 lines/wave-load ----
    const size_t base = (size_t)b * L_ * C_ + g * 16;
    int lrow = tid >> 2;              // 0..63
    int lq   = tid & 3;               // quad within 16 channels
    #pragma unroll
    for (int it = 0; it < 4; ++it) {
        int r   = lrow + (it << 6);                     // row = n1*16 + n2loc
        int tau = ((r >> 4) << 8) + (w << 4) + (r & 15);
        const float4 q4 = *(const float4*)(q + base + (size_t)tau * C_ + (lq << 2));
        const float4 k4 = *(const float4*)(k + base + (size_t)tau * C_ + (lq << 2));
        float2* dst = &s2[r * 17 + (lq << 2)];
        dst[0] = make_float2(q4.x, k4.x);
        dst[1] = make_float2(q4.y, k4.y);
        dst[2] = make_float2(q4.z, k4.z);
        dst[3] = make_float2(q4.w, k4.w);
    }
    __syncthreads();

    // ---- compute: thread = (ch = tid>>4, n2loc = tid&15) ----
    int ch = tid >> 4, n2loc = tid & 15;
    int n2 = (w << 4) + n2loc;
    float2 a[16];
    int rbase = n2loc * 17 + ch;
    #pragma unroll
    for (int n1 = 0; n1 < 16; ++n1) a[n1] = s2[n1 * 272 + rbase];
    fft16(a);
    // twiddle W4096^{n2*k1}: 4 independent chains stepped by w4 = W^{4*n2}
    float sn, cs;
    sincospif((float)n2 / 2048.0f, &sn, &cs);
    const float2 w1 = make_float2(cs, -sn);
    const float2 w2 = cmul(w1, w1);
    const float2 w4 = cmul(w2, w2);
    float2 tws[4] = {w1, w2, cmul(w2, w1), w4};
    float2* zc = z + ((size_t)bl * C_ + (g * 16 + ch)) * L_ + n2;
    zc[0] = a[0];                      // k1 = 0 (br4[0]=0, tw=1)
    #pragma unroll
    for (int k1 = 1; k1 < 16; ++k1) {
        int j = (k1 - 1) & 3;
        zc[(size_t)(k1 << 8)] = cmul(a[br4[k1]], tws[j]);
        tws[j] = cmul(tws[j], w4);
    }
}

// ---------------- FFT phases B+C + cross-spectrum accumulate (half spectrum) ----------------
// z[c][k1*256+n2] holds phase-A output (twiddled). Conjugate symmetry
// S(L-p)=conj(S(p)) -> bins 0..2047 + Nyquist only. Tail: contention-free
// partial stores (r11/r12: device atomics were the fused variants' binding
// constraint). NEW vs r13: after phase C, thread t already HOLDS its accum
// bins X[r2*256+t] in registers (r1C*16+k1C == t), so the accumulate reads
// only the 8 conjugate-partner values from column 256-t (lane-consecutive,
// conflict-free) instead of 33 LDS reads; self values saved to sv[9] before
// the prefetch clobbers a[]. Saves 25 LDS reads x 8 channels per thread.
__global__ __launch_bounds__(256) void k_fft_bc(const float2* __restrict__ z,
                                                float2* __restrict__ part,
                                                int b0) {
    __shared__ float2 s[16 * RPAD];
    __shared__ float2 tw256[256];     // tw256[r1*16+m2] = W256^{m2*r1}
    const int br4[16] = {0, 8, 4, 12, 2, 10, 6, 14, 1, 9, 5, 13, 3, 11, 7, 15};
    int t  = threadIdx.x;
    int bl = blockIdx.y;
    int b  = b0 + bl;
    int g  = blockIdx.x;              // channel group of 8
    int c0 = g * 8;

    {
        int r1 = t >> 4, m2 = t & 15;
        float sn, cs;
        sincospif((float)(r1 * m2) / 128.0f, &sn, &cs);
        tw256[t] = make_float2(cs, -sn);
    }
    float accx[8], accy[8], accN = 0.f;
    #pragma unroll
    for (int r = 0; r < 8; ++r) { accx[r] = 0.f; accy[r] = 0.f; }

    const int rowB = t >> 4, m2B = t & 15;
    const int k1C = t & 15, r1C = t >> 4;

    // prefetch channel 0 (stays in flight across the setup barrier)
    float2 a[16];
    {
        const float2* zc0 = z + ((size_t)bl * C_ + c0) * L_;
        #pragma unroll
        for (int m1 = 0; m1 < 16; ++m1) a[m1] = zc0[(rowB << 8) + (m1 << 4) + m2B];
    }
    bar_lds();   // tw256 ready

    for (int cc = 0; cc < 8; ++cc) {
        // ---- phase B (input prefetched in a[]) ----
        fft16(a);
        #pragma unroll
        for (int r1 = 0; r1 < 16; ++r1)
            s[rowB * RPAD + (r1 << 4) + m2B] = cmul(a[br4[r1]], tw256[(r1 << 4) + m2B]);
        bar_lds();
        // ---- phase C ----
        #pragma unroll
        for (int m2 = 0; m2 < 16; ++m2) a[m2] = s[k1C * RPAD + (r1C << 4) + m2];
        fft16(a);
        bar_lds();   // all threads' C-reads retired before col-stores overwrite s
        // ---- column store: X[r2*256+t] -> s[r2*RPAD + t] (conflict-free) ----
        #pragma unroll
        for (int r2 = 0; r2 < 16; ++r2)
            s[r2 * RPAD + t] = a[br4[r2]];
        // save self values the accumulate needs before prefetch clobbers a[]
        float2 sv[9];
        sv[0] = a[0];  sv[1] = a[8];  sv[2] = a[4];  sv[3] = a[12];
        sv[4] = a[2];  sv[5] = a[10]; sv[6] = a[6];  sv[7] = a[14];
        sv[8] = a[1];                 // bin 2048 holder (t==0 only uses it)
        // ---- prefetch next channel into now-dead a[] ----
        if (cc < 7) {
            const float2* zn = z + ((size_t)bl * C_ + (c0 + cc + 1)) * L_;
            #pragma unroll
            for (int m1 = 0; m1 < 16; ++m1) a[m1] = zn[(rowB << 8) + (m1 << 4) + m2B];
        }
        bar_lds();   // col-stores visible; prefetch stays in flight
        // ---- accumulate Q*conj(K): self from sv, partner from column 256-t ----
        #pragma unroll
        for (int r = 0; r < 8; ++r) {
            float2 A  = sv[r];                        // X[r*256 + t]
            float2 Bv = (t == 0) ? s[((16 - r) & 15) * RPAD]
                                 : s[(15 - r) * RPAD + (256 - t)];  // X[4096 - r*256 - t]
            float Qr = 0.5f * (A.x + Bv.x);
            float Qi = 0.5f * (A.y - Bv.y);
            float Kr = 0.5f * (A.y + Bv.y);
            float Ki = 0.5f * (A.x - Bv.x);
            accx[r] += Qr * Kr - Qi * Ki;
            accy[r] += Qr * Ki + Qi * Kr;
        }
        if (t == 0) accN += sv[8].x * sv[8].y;        // Nyquist: Q,K real there
        bar_lds();   // partner reads done before next phase B overwrites s
    }
    // ---- contention-free coalesced partial stores (no atomics) ----
    float2* pb = part + (size_t)(b * G_ + g) * PSTRIDE;
    #pragma unroll
    for (int r = 0; r < 8; ++r)
        pb[t + (r << 8)] = make_float2(accx[r], accy[r]);
    if (t == 0) pb[2048] = make_float2(accN, 0.f);
}

// ---------------- partial-spectrum reduction: cross[b][p] = sum_g part[b][g][p] ----------------
__global__ __launch_bounds__(256) void k_reduce(const float2* __restrict__ part,
                                                float* __restrict__ cross) {
    __shared__ float2 acc2[128];
    int b  = blockIdx.x;
    int pt = blockIdx.y;
    int t  = threadIdx.x;
    int pi = t & 127, gh = t >> 7;
    int p  = pt * 128 + pi;
    float sx = 0.f, sy = 0.f;
    if (p <= 2048) {
        const float2* base = part + ((size_t)b * G_ + gh * 32) * PSTRIDE + p;
        #pragma unroll 4
        for (int g = 0; g < 32; ++g) {
            float2 v = base[(size_t)g * PSTRIDE];
            sx += v.x; sy += v.y;
        }
    }
    if (gh == 1) acc2[pi] = make_float2(sx, sy);
    __syncthreads();
    if (gh == 0 && p <= 2048) {
        float2 o = acc2[pi];
        ((float2*)cross)[(size_t)b * L_ + p] = make_float2(sx + o.x, sy + o.y);
    }
}

// ---------------- inverse FFT via conj-forward 3-phase radix-16 ----------------
// cross holds only bins 0..2048; upper half reconstructed via S(L-p)=conj(S(p)).
__global__ __launch_bounds__(256) void k_ifft(const float* __restrict__ cross,
                                              float* __restrict__ mv) {
    __shared__ float2 s[16 * RPAD];
    __shared__ float2 tw256[256];
    const int br4[16] = {0, 8, 4, 12, 2, 10, 6, 14, 1, 9, 5, 13, 3, 11, 7, 15};
    int t = threadIdx.x;
    int b = blockIdx.x;
    {
        int r1 = t >> 4, m2 = t & 15;
        float sn, cs;
        sincospif((float)(r1 * m2) / 128.0f, &sn, &cs);
        tw256[t] = make_float2(cs, -sn);
    }
    const float2* cr = (const float2*)cross + (size_t)b * L_;
    float2 a[16];
    #pragma unroll
    for (int n1 = 0; n1 < 16; ++n1) {
        int P = (n1 << 8) + t;
        int hi = P > 2048;
        float2 v = cr[hi ? (L_ - P) : P];
        // want a = conj(S(P)): P<=2048 -> conj(v); P>2048 -> S(P)=conj(v) -> a = v
        a[n1] = hi ? v : make_float2(v.x, -v.y);
    }
    // ---- phase A ----
    fft16(a);
    {
        float sn, cs;
        sincospif((float)t / 2048.0f, &sn, &cs);
        const float2 w1 = make_float2(cs, -sn);
        float2 tw = w1;
        s[t] = a[0];
        #pragma unroll
        for (int k1 = 1; k1 < 16; ++k1) {
            s[k1 * RPAD + t] = cmul(a[br4[k1]], tw);
            tw = cmul(tw, w1);
        }
    }
    __syncthreads();
    // ---- phase B ----
    const int rowB = t >> 4, m2B = t & 15;
    #pragma unroll
    for (int m1 = 0; m1 < 16; ++m1) a[m1] = s[rowB * RPAD + (m1 << 4) + m2B];
    fft16(a);
    #pragma unroll
    for (int r1 = 0; r1 < 16; ++r1)
        s[rowB * RPAD + (r1 << 4) + m2B] = cmul(a[br4[r1]], tw256[(r1 << 4) + m2B]);
    __syncthreads();
    // ---- phase C: write mv directly (k = r2*256 + t, coalesced) ----
    const int k1C = t & 15, r1C = t >> 4;
    #pragma unroll
    for (int m2 = 0; m2 < 16; ++m2) a[m2] = s[k1C * RPAD + (r1C << 4) + m2];
    fft16(a);
    const float scale = 1.0f / ((float)L_ * (float)C_);
    #pragma unroll
    for (int r2 = 0; r2 < 16; ++r2)
        mv[(size_t)b * L_ + (r2 << 8) + t] = a[br4[r2]].x * scale;
}

// ---------------- top-24 + per-batch softmax (register-resident, wave-shuffle) ----------------
__global__ __launch_bounds__(256) void k_topk(const float* __restrict__ mv,
                                              int* __restrict__ idx,
                                              float* __restrict__ wts) {
    __shared__ float wv[4];
    __shared__ int   wi[4];
    __shared__ int   idxL[K_];
    int tid = threadIdx.x;
    float vloc[16];
    #pragma unroll
    for (int r = 0; r < 16; ++r) {
        int tt = tid + (r << 8);
        float ssum = 0.f;
        for (int b = 0; b < B_; ++b) ssum += mv[(size_t)b * L_ + tt];
        vloc[r] = ssum;
    }
    int lane = tid & 63, w = tid >> 6;
    for (int i = 0; i < K_; ++i) {
        float best = -INFINITY; int bi = 1 << 30;
        #pragma unroll
        for (int r = 0; r < 16; ++r) {
            float v = vloc[r]; int ii = tid + (r << 8);
            if (v > best || (v == best && ii < bi)) { best = v; bi = ii; }
        }
        #pragma unroll
        for (int off = 32; off > 0; off >>= 1) {
            float ov = __shfl_down(best, off);
            int   oi = __shfl_down(bi, off);
            if (ov > best || (ov == best && oi < bi)) { best = ov; bi = oi; }
        }
        if (lane == 0) { wv[w] = best; wi[w] = bi; }
        __syncthreads();
        if (tid == 0) {
            float bb = wv[0]; int bj = wi[0];
            for (int j = 1; j < 4; ++j)
                if (wv[j] > bb || (wv[j] == bb && wi[j] < bj)) { bb = wv[j]; bj = wi[j]; }
            idxL[i] = bj; idx[i] = bj;
        }
        __syncthreads();
        int win = idxL[i];
        #pragma unroll
        for (int r = 0; r < 16; ++r)
            if (win == tid + (r << 8)) vloc[r] = -INFINITY;
    }
    if (tid < B_) {
        int b = tid;
        float ww[K_]; float wm = -INFINITY;
        for (int i = 0; i < K_; ++i) { ww[i] = mv[(size_t)b * L_ + idxL[i]]; wm = fmaxf(wm, ww[i]); }
        float ssum = 0.f;
        for (int i = 0; i < K_; ++i) { ww[i] = expf(ww[i] - wm); ssum += ww[i]; }
        float inv = 1.f / ssum;
        for (int i = 0; i < K_; ++i) wts[b * K_ + i] = ww[i] * inv;
    }
}

// ---------------- 24-tap circulant gather-sum, LDS tau-ring version ----------------
__global__ __launch_bounds__(256) void k_agg(const float* __restrict__ vals,
                                             const int* __restrict__ idx,
                                             const float* __restrict__ wts,
                                             float* __restrict__ out) {
    __shared__ float4 sv[L_];      // 64 KB ring: 2 blocks/CU
    __shared__ int   di[K_];
    __shared__ float dw[K_];
    const int tid = threadIdx.x;
    // XCD-aware bijective decode: 2048 blocks; xcd = id&7 owns work [xcd*256, xcd*256+256)
    int id = blockIdx.x;
    int wk = ((id & 7) << 8) | (id >> 3);
    int b  = wk >> 7;              // 0..15 (2 batches per XCD)
    int c0 = (wk & 127) << 2;      // channel-quad start

    if (tid < K_) { di[tid] = idx[tid]; dw[tid] = wts[b * K_ + tid]; }

    // ---- stage: 16 iters x 256 lanes x 16B, LDS dest linear (wave-uniform base + lane*16)
    const float* gbase = vals + (size_t)b * L_ * C_ + c0;
    #pragma unroll
    for (int it = 0; it < 16; ++it) {
        int tau = (it << 8) + tid;
        const float* g = gbase + (size_t)tau * C_;
        float4* l = &sv[(it << 8) + ((tid >> 6) << 6)];   // wave-uniform within each wave
        __builtin_amdgcn_global_load_lds(
            (const __attribute__((address_space(1))) uint32_t*)g,
            (__attribute__((address_space(3))) uint32_t*)l,
            16, 0, 0);
    }
    __syncthreads();   // drains vmcnt before barrier

    // taps/weights to registers (fully-unrolled static indexing)
    int   dir[K_]; float dwr[K_];
    #pragma unroll
    for (int i = 0; i < K_; ++i) { dir[i] = di[i]; dwr[i] = dw[i]; }

    float* obase = out + (size_t)b * L_ * C_ + c0;
    for (int r = 0; r < 16; ++r) {
        int tau = (r << 8) + tid;
        float4 acc = make_float4(0.f, 0.f, 0.f, 0.f);
        #pragma unroll
        for (int i = 0; i < K_; ++i) {
            float4 x = sv[(tau + dir[i]) & (L_ - 1)];
            float w = dwr[i];
            acc.x = fmaf(w, x.x, acc.x);
            acc.y = fmaf(w, x.y, acc.y);
            acc.z = fmaf(w, x.z, acc.z);
            acc.w = fmaf(w, x.w, acc.w);
        }
        *(float4*)(obase + (size_t)tau * C_) = acc;
    }
}

extern "C" void kernel_launch(void* const* d_in, const int* in_sizes, int n_in,
                              void* d_out, int out_size, void* d_ws, size_t ws_size,
                              hipStream_t stream) {
    const float* q = (const float*)d_in[0];
    const float* k = (const float*)d_in[1];
    const float* v = (const float*)d_in[2];
    float* out = (float*)d_out;
    char* ws = (char*)d_ws;

    // ws layout: [cross 512KB | mv 256KB | idx | wts | part at 2MB (16.8MB) | z at 20MB]
    float*  cross = (float*)ws;
    float*  mv    = (float*)(ws + (1 << 20));
    int*    idx   = (int*)(ws + (1 << 20) + (1 << 18));
    float*  wts   = (float*)(ws + (1 << 20) + (1 << 18) + 4096);
    float2* part  = (float2*)(ws + (2 << 20));
    float2* z     = (float2*)(ws + (size_t)(20 << 20));

    size_t zcap = (ws_size > (size_t)(20 << 20)) ? ws_size - (size_t)(20 << 20) : 0;
    int P = 16;
    while (P > 1 && (size_t)P * C_ * L_ * sizeof(float2) > zcap) P >>= 1;
    // P=8 chunking: z chunk = 128MB < 256MB L3 -> fft_bc reads z from Infinity
    // Cache instead of HBM; also halves per-dispatch dur so fft_bc/agg become
    // visible in the profile top-5.
    if (P > 8) P = 8;

    for (int b0 = 0; b0 < B_; b0 += P) {
        dim3 g1(16, 32, P);   // n2 windows x ch groups x batches
        k_phaseA<<<g1, 256, 0, stream>>>(q, k, z, b0);
        dim3 g2(G_, P);
        k_fft_bc<<<g2, 256, 0, stream>>>(z, part, b0);
    }
    dim3 gr(B_, 17);
    k_reduce<<<gr, 256, 0, stream>>>(part, cross);
    k_ifft<<<B_, 256, 0, stream>>>(cross, mv);
    k_topk<<<1, 256, 0, stream>>>(mv, idx, wts);
    k_agg<<<B_ * (C_ / 4), 256, 0, stream>>>(v, idx, wts, out);
}

// Round 16
// 310.879 us; speedup vs baseline: 1.0677x; 1.0625x over previous
//
#include <hip/hip_runtime.h>
#include <hip/hip_fp16.h>
#include <math.h>

#define B_ 16
#define L_ 4096
#define H_ 8
#define E_ 64
#define C_ 512     // H*E
#define K_ 24
#define NT 256
#define RPAD 257      // padded row stride (float2 units) for the 16x256 LDS matrix
#define PSTRIDE 2052  // partial-spectrum row stride (float2), bins 0..2048 used
#define G_ 64         // channel groups (8 ch each) per batch for fft_bc

__device__ __forceinline__ float2 cmul(float2 a, float2 b) {
    return make_float2(a.x * b.x - a.y * b.y, a.x * b.y + a.y * b.x);
}
__device__ __forceinline__ float2 cadd(float2 a, float2 b) { return make_float2(a.x + b.x, a.y + b.y); }
__device__ __forceinline__ float2 csub(float2 a, float2 b) { return make_float2(a.x - b.x, a.y - b.y); }

// barrier that orders LDS only: does NOT drain vmcnt, so register prefetch
// loads stay in flight across it (no cross-thread global deps at these points)
__device__ __forceinline__ void bar_lds() {
    asm volatile("s_waitcnt lgkmcnt(0)" ::: "memory");
    __builtin_amdgcn_s_barrier();
}

// 16-point DIF FFT, natural-order input; output: X[k] = a[br4[k]]
__device__ __forceinline__ void fft16(float2 a[16]) {
    const float r2 = 0.70710678118654752f;
    const float c1 = 0.92387953251128676f;  // cos(pi/8)
    const float s1 = 0.38268343236508977f;  // sin(pi/8)
    const float2 W16[8] = {
        make_float2(1.f, 0.f),  make_float2(c1, -s1),  make_float2(r2, -r2),  make_float2(s1, -c1),
        make_float2(0.f, -1.f), make_float2(-s1, -c1), make_float2(-r2, -r2), make_float2(-c1, -s1)};
    #pragma unroll
    for (int j = 0; j < 8; ++j) {
        float2 u = a[j], v = a[j + 8];
        a[j]     = cadd(u, v);
        a[j + 8] = cmul(csub(u, v), W16[j]);
    }
    #pragma unroll
    for (int b = 0; b < 16; b += 8)
        #pragma unroll
        for (int j = 0; j < 4; ++j) {
            float2 u = a[b + j], v = a[b + j + 4];
            a[b + j]     = cadd(u, v);
            a[b + j + 4] = cmul(csub(u, v), W16[2 * j]);
        }
    #pragma unroll
    for (int b = 0; b < 16; b += 4)
        #pragma unroll
        for (int j = 0; j < 2; ++j) {
            float2 u = a[b + j], v = a[b + j + 2];
            a[b + j]     = cadd(u, v);
            a[b + j + 2] = cmul(csub(u, v), W16[4 * j]);
        }
    #pragma unroll
    for (int b = 0; b < 16; b += 2) {
        float2 u = a[b], v = a[b + 1];
        a[b]     = cadd(u, v);
        a[b + 1] = csub(u, v);
    }
}

// ---------------- fused transpose + FFT phase A (r13 structure, fp16 z output) ----------------
// r13/r14: this structure runs at the chip's transpose ceiling (~3.1 TB/s);
// pipelining attempts regressed it. NEW: z stored as fp16 (half2 per complex)
// -> z round-trip halves (512MB -> 256MB). Precision: z ~ +-300 max, fp16
// rel err 5e-4; mv averages 512 channels -> topk scores err ~2e-5. Writes
// remain full-64B-line efficient (16 consecutive n2 x 4B per channel row).
__global__ __launch_bounds__(256) void k_phaseA(const float* __restrict__ q,
                                                const float* __restrict__ k,
                                                __half2* __restrict__ z,
                                                int b0) {
    __shared__ float2 s2[256 * 17];   // [row = n1*16 + n2loc][ch], stride 17 -> 34.8 KB
    const int br4[16] = {0, 8, 4, 12, 2, 10, 6, 14, 1, 9, 5, 13, 3, 11, 7, 15};
    int w  = blockIdx.x;              // n2 window (16 of them)
    int g  = blockIdx.y;              // channel group of 16 (32 of them)
    int bl = blockIdx.z;
    int b  = b0 + bl;
    int tid = threadIdx.x;

    // ---- load 256 rows x 16 ch, float4 per (row, quad): 16 lines/wave-load ----
    const size_t base = (size_t)b * L_ * C_ + g * 16;
    int lrow = tid >> 2;              // 0..63
    int lq   = tid & 3;               // quad within 16 channels
    #pragma unroll
    for (int it = 0; it < 4; ++it) {
        int r   = lrow + (it << 6);                     // row = n1*16 + n2loc
        int tau = ((r >> 4) << 8) + (w << 4) + (r & 15);
        const float4 q4 = *(const float4*)(q + base + (size_t)tau * C_ + (lq << 2));
        const float4 k4 = *(const float4*)(k + base + (size_t)tau * C_ + (lq << 2));
        float2* dst = &s2[r * 17 + (lq << 2)];
        dst[0] = make_float2(q4.x, k4.x);
        dst[1] = make_float2(q4.y, k4.y);
        dst[2] = make_float2(q4.z, k4.z);
        dst[3] = make_float2(q4.w, k4.w);
    }
    __syncthreads();

    // ---- compute: thread = (ch = tid>>4, n2loc = tid&15) ----
    int ch = tid >> 4, n2loc = tid & 15;
    int n2 = (w << 4) + n2loc;
    float2 a[16];
    int rbase = n2loc * 17 + ch;
    #pragma unroll
    for (int n1 = 0; n1 < 16; ++n1) a[n1] = s2[n1 * 272 + rbase];
    fft16(a);
    // twiddle W4096^{n2*k1}: 4 independent chains stepped by w4 = W^{4*n2}
    float sn, cs;
    sincospif((float)n2 / 2048.0f, &sn, &cs);
    const float2 w1 = make_float2(cs, -sn);
    const float2 w2 = cmul(w1, w1);
    const float2 w4 = cmul(w2, w2);
    float2 tws[4] = {w1, w2, cmul(w2, w1), w4};
    __half2* zc = z + ((size_t)bl * C_ + (g * 16 + ch)) * L_ + n2;
    zc[0] = __float22half2_rn(a[0]);   // k1 = 0 (br4[0]=0, tw=1)
    #pragma unroll
    for (int k1 = 1; k1 < 16; ++k1) {
        int j = (k1 - 1) & 3;
        zc[(size_t)(k1 << 8)] = __float22half2_rn(cmul(a[br4[k1]], tws[j]));
        tws[j] = cmul(tws[j], w4);
    }
}

// ---------------- FFT phases B+C + cross-spectrum accumulate (half spectrum) ----------------
// z (fp16 half2) -> float on prefetch. Conjugate symmetry -> bins 0..2047 +
// Nyquist only. r15 structure: after phase C, thread t holds its accum bins
// X[r2*256+t] in registers (saved to sv[9]); accumulate reads only the 8
// conjugate partners from column 256-t. Tail: contention-free partial stores.
__global__ __launch_bounds__(256) void k_fft_bc(const __half2* __restrict__ z,
                                                float2* __restrict__ part,
                                                int b0) {
    __shared__ float2 s[16 * RPAD];
    __shared__ float2 tw256[256];     // tw256[r1*16+m2] = W256^{m2*r1}
    const int br4[16] = {0, 8, 4, 12, 2, 10, 6, 14, 1, 9, 5, 13, 3, 11, 7, 15};
    int t  = threadIdx.x;
    int bl = blockIdx.y;
    int b  = b0 + bl;
    int g  = blockIdx.x;              // channel group of 8
    int c0 = g * 8;

    {
        int r1 = t >> 4, m2 = t & 15;
        float sn, cs;
        sincospif((float)(r1 * m2) / 128.0f, &sn, &cs);
        tw256[t] = make_float2(cs, -sn);
    }
    float accx[8], accy[8], accN = 0.f;
    #pragma unroll
    for (int r = 0; r < 8; ++r) { accx[r] = 0.f; accy[r] = 0.f; }

    const int rowB = t >> 4, m2B = t & 15;
    const int k1C = t & 15, r1C = t >> 4;

    // prefetch channel 0 (stays in flight across the setup barrier)
    float2 a[16];
    {
        const __half2* zc0 = z + ((size_t)bl * C_ + c0) * L_;
        #pragma unroll
        for (int m1 = 0; m1 < 16; ++m1)
            a[m1] = __half22float2(zc0[(rowB << 8) + (m1 << 4) + m2B]);
    }
    bar_lds();   // tw256 ready

    for (int cc = 0; cc < 8; ++cc) {
        // ---- phase B (input prefetched in a[]) ----
        fft16(a);
        #pragma unroll
        for (int r1 = 0; r1 < 16; ++r1)
            s[rowB * RPAD + (r1 << 4) + m2B] = cmul(a[br4[r1]], tw256[(r1 << 4) + m2B]);
        bar_lds();
        // ---- phase C ----
        #pragma unroll
        for (int m2 = 0; m2 < 16; ++m2) a[m2] = s[k1C * RPAD + (r1C << 4) + m2];
        fft16(a);
        bar_lds();   // all threads' C-reads retired before col-stores overwrite s
        // ---- column store: X[r2*256+t] -> s[r2*RPAD + t] (conflict-free) ----
        #pragma unroll
        for (int r2 = 0; r2 < 16; ++r2)
            s[r2 * RPAD + t] = a[br4[r2]];
        // save self values the accumulate needs before prefetch clobbers a[]
        float2 sv[9];
        sv[0] = a[0];  sv[1] = a[8];  sv[2] = a[4];  sv[3] = a[12];
        sv[4] = a[2];  sv[5] = a[10]; sv[6] = a[6];  sv[7] = a[14];
        sv[8] = a[1];                 // bin 2048 holder (t==0 only uses it)
        // ---- prefetch next channel into now-dead a[] ----
        if (cc < 7) {
            const __half2* zn = z + ((size_t)bl * C_ + (c0 + cc + 1)) * L_;
            #pragma unroll
            for (int m1 = 0; m1 < 16; ++m1)
                a[m1] = __half22float2(zn[(rowB << 8) + (m1 << 4) + m2B]);
        }
        bar_lds();   // col-stores visible; prefetch stays in flight
        // ---- accumulate Q*conj(K): self from sv, partner from column 256-t ----
        #pragma unroll
        for (int r = 0; r < 8; ++r) {
            float2 A  = sv[r];                        // X[r*256 + t]
            float2 Bv = (t == 0) ? s[((16 - r) & 15) * RPAD]
                                 : s[(15 - r) * RPAD + (256 - t)];  // X[4096 - r*256 - t]
            float Qr = 0.5f * (A.x + Bv.x);
            float Qi = 0.5f * (A.y - Bv.y);
            float Kr = 0.5f * (A.y + Bv.y);
            float Ki = 0.5f * (A.x - Bv.x);
            accx[r] += Qr * Kr - Qi * Ki;
            accy[r] += Qr * Ki + Qi * Kr;
        }
        if (t == 0) accN += sv[8].x * sv[8].y;        // Nyquist: Q,K real there
        bar_lds();   // partner reads done before next phase B overwrites s
    }
    // ---- contention-free coalesced partial stores (no atomics) ----
    float2* pb = part + (size_t)(b * G_ + g) * PSTRIDE;
    #pragma unroll
    for (int r = 0; r < 8; ++r)
        pb[t + (r << 8)] = make_float2(accx[r], accy[r]);
    if (t == 0) pb[2048] = make_float2(accN, 0.f);
}

// ---------------- partial-spectrum reduction: cross[b][p] = sum_g part[b][g][p] ----------------
__global__ __launch_bounds__(256) void k_reduce(const float2* __restrict__ part,
                                                float* __restrict__ cross) {
    __shared__ float2 acc2[128];
    int b  = blockIdx.x;
    int pt = blockIdx.y;
    int t  = threadIdx.x;
    int pi = t & 127, gh = t >> 7;
    int p  = pt * 128 + pi;
    float sx = 0.f, sy = 0.f;
    if (p <= 2048) {
        const float2* base = part + ((size_t)b * G_ + gh * 32) * PSTRIDE + p;
        #pragma unroll 4
        for (int g = 0; g < 32; ++g) {
            float2 v = base[(size_t)g * PSTRIDE];
            sx += v.x; sy += v.y;
        }
    }
    if (gh == 1) acc2[pi] = make_float2(sx, sy);
    __syncthreads();
    if (gh == 0 && p <= 2048) {
        float2 o = acc2[pi];
        ((float2*)cross)[(size_t)b * L_ + p] = make_float2(sx + o.x, sy + o.y);
    }
}

// ---------------- inverse FFT via conj-forward 3-phase radix-16 ----------------
// cross holds only bins 0..2048; upper half reconstructed via S(L-p)=conj(S(p)).
__global__ __launch_bounds__(256) void k_ifft(const float* __restrict__ cross,
                                              float* __restrict__ mv) {
    __shared__ float2 s[16 * RPAD];
    __shared__ float2 tw256[256];
    const int br4[16] = {0, 8, 4, 12, 2, 10, 6, 14, 1, 9, 5, 13, 3, 11, 7, 15};
    int t = threadIdx.x;
    int b = blockIdx.x;
    {
        int r1 = t >> 4, m2 = t & 15;
        float sn, cs;
        sincospif((float)(r1 * m2) / 128.0f, &sn, &cs);
        tw256[t] = make_float2(cs, -sn);
    }
    const float2* cr = (const float2*)cross + (size_t)b * L_;
    float2 a[16];
    #pragma unroll
    for (int n1 = 0; n1 < 16; ++n1) {
        int P = (n1 << 8) + t;
        int hi = P > 2048;
        float2 v = cr[hi ? (L_ - P) : P];
        // want a = conj(S(P)): P<=2048 -> conj(v); P>2048 -> S(P)=conj(v) -> a = v
        a[n1] = hi ? v : make_float2(v.x, -v.y);
    }
    // ---- phase A ----
    fft16(a);
    {
        float sn, cs;
        sincospif((float)t / 2048.0f, &sn, &cs);
        const float2 w1 = make_float2(cs, -sn);
        float2 tw = w1;
        s[t] = a[0];
        #pragma unroll
        for (int k1 = 1; k1 < 16; ++k1) {
            s[k1 * RPAD + t] = cmul(a[br4[k1]], tw);
            tw = cmul(tw, w1);
        }
    }
    __syncthreads();
    // ---- phase B ----
    const int rowB = t >> 4, m2B = t & 15;
    #pragma unroll
    for (int m1 = 0; m1 < 16; ++m1) a[m1] = s[rowB * RPAD + (m1 << 4) + m2B];
    fft16(a);
    #pragma unroll
    for (int r1 = 0; r1 < 16; ++r1)
        s[rowB * RPAD + (r1 << 4) + m2B] = cmul(a[br4[r1]], tw256[(r1 << 4) + m2B]);
    __syncthreads();
    // ---- phase C: write mv directly (k = r2*256 + t, coalesced) ----
    const int k1C = t & 15, r1C = t >> 4;
    #pragma unroll
    for (int m2 = 0; m2 < 16; ++m2) a[m2] = s[k1C * RPAD + (r1C << 4) + m2];
    fft16(a);
    const float scale = 1.0f / ((float)L_ * (float)C_);
    #pragma unroll
    for (int r2 = 0; r2 < 16; ++r2)
        mv[(size_t)b * L_ + (r2 << 8) + t] = a[br4[r2]].x * scale;
}

// ---------------- top-24 + per-batch softmax (register-resident, wave-shuffle) ----------------
__global__ __launch_bounds__(256) void k_topk(const float* __restrict__ mv,
                                              int* __restrict__ idx,
                                              float* __restrict__ wts) {
    __shared__ float wv[4];
    __shared__ int   wi[4];
    __shared__ int   idxL[K_];
    int tid = threadIdx.x;
    float vloc[16];
    #pragma unroll
    for (int r = 0; r < 16; ++r) {
        int tt = tid + (r << 8);
        float ssum = 0.f;
        for (int b = 0; b < B_; ++b) ssum += mv[(size_t)b * L_ + tt];
        vloc[r] = ssum;
    }
    int lane = tid & 63, w = tid >> 6;
    for (int i = 0; i < K_; ++i) {
        float best = -INFINITY; int bi = 1 << 30;
        #pragma unroll
        for (int r = 0; r < 16; ++r) {
            float v = vloc[r]; int ii = tid + (r << 8);
            if (v > best || (v == best && ii < bi)) { best = v; bi = ii; }
        }
        #pragma unroll
        for (int off = 32; off > 0; off >>= 1) {
            float ov = __shfl_down(best, off);
            int   oi = __shfl_down(bi, off);
            if (ov > best || (ov == best && oi < bi)) { best = ov; bi = oi; }
        }
        if (lane == 0) { wv[w] = best; wi[w] = bi; }
        __syncthreads();
        if (tid == 0) {
            float bb = wv[0]; int bj = wi[0];
            for (int j = 1; j < 4; ++j)
                if (wv[j] > bb || (wv[j] == bb && wi[j] < bj)) { bb = wv[j]; bj = wi[j]; }
            idxL[i] = bj; idx[i] = bj;
        }
        __syncthreads();
        int win = idxL[i];
        #pragma unroll
        for (int r = 0; r < 16; ++r)
            if (win == tid + (r << 8)) vloc[r] = -INFINITY;
    }
    if (tid < B_) {
        int b = tid;
        float ww[K_]; float wm = -INFINITY;
        for (int i = 0; i < K_; ++i) { ww[i] = mv[(size_t)b * L_ + idxL[i]]; wm = fmaxf(wm, ww[i]); }
        float ssum = 0.f;
        for (int i = 0; i < K_; ++i) { ww[i] = expf(ww[i] - wm); ssum += ww[i]; }
        float inv = 1.f / ssum;
        for (int i = 0; i < K_; ++i) wts[b * K_ + i] = ww[i] * inv;
    }
}

// ---------------- 24-tap circulant gather-sum, fp16 LDS tau-ring ----------------
// r15 post-mortem: k_agg = 117us at 1.7 TB/s effective, Occupancy 19%,
// VALU 24% — scatter-staging-latency bound with only 2 blocks/CU (66KB LDS).
// Fix: V ring in fp16 (half2[4096][2] = 32KB -> 4 blocks/CU = 2x TLP);
// reg-staged loads in two 8-deep batches keep all 16 loads in flight.
// Accumulate converts on read (VALU had 3x headroom). Precision: fp16 rel
// err 5e-4 on V, weights sum to 1 -> output err ~5e-4 << 0.0156 absmax.
__global__ __launch_bounds__(256) void k_agg(const float* __restrict__ vals,
                                             const int* __restrict__ idx,
                                             const float* __restrict__ wts,
                                             float* __restrict__ out) {
    __shared__ __half2 sv2[L_][2];  // 32 KB ring: tau x 4ch fp16 -> 4 blocks/CU
    __shared__ int   di[K_];
    __shared__ float dw[K_];
    const int tid = threadIdx.x;
    // XCD-aware bijective decode: 2048 blocks; xcd = id&7 owns 2 whole batches
    int id = blockIdx.x;
    int wk = ((id & 7) << 8) | (id >> 3);
    int b  = wk >> 7;              // 0..15
    int c0 = (wk & 127) << 2;      // channel-quad start

    if (tid < K_) { di[tid] = idx[tid]; dw[tid] = wts[b * K_ + tid]; }

    // ---- stage: two 8-deep reg batches (32 VGPR), cvt to fp16, LDS write ----
    const float* gbase = vals + (size_t)b * L_ * C_ + c0;
    #pragma unroll
    for (int sr = 0; sr < 2; ++sr) {
        float4 xv[8];
        #pragma unroll
        for (int it = 0; it < 8; ++it) {
            int tau = (((sr << 3) + it) << 8) + tid;
            xv[it] = *(const float4*)(gbase + (size_t)tau * C_);
        }
        #pragma unroll
        for (int it = 0; it < 8; ++it) {
            int tau = (((sr << 3) + it) << 8) + tid;
            sv2[tau][0] = __float22half2_rn(make_float2(xv[it].x, xv[it].y));
            sv2[tau][1] = __float22half2_rn(make_float2(xv[it].z, xv[it].w));
        }
    }
    __syncthreads();

    // taps/weights to registers (fully-unrolled static indexing)
    int   dir[K_]; float dwr[K_];
    #pragma unroll
    for (int i = 0; i < K_; ++i) { dir[i] = di[i]; dwr[i] = dw[i]; }

    float* obase = out + (size_t)b * L_ * C_ + c0;
    for (int r = 0; r < 16; ++r) {
        int tau = (r << 8) + tid;
        float4 acc = make_float4(0.f, 0.f, 0.f, 0.f);
        #pragma unroll
        for (int i = 0; i < K_; ++i) {
            int row = (tau + dir[i]) & (L_ - 1);
            float2 x0 = __half22float2(sv2[row][0]);
            float2 x1 = __half22float2(sv2[row][1]);
            float w = dwr[i];
            acc.x = fmaf(w, x0.x, acc.x);
            acc.y = fmaf(w, x0.y, acc.y);
            acc.z = fmaf(w, x1.x, acc.z);
            acc.w = fmaf(w, x1.y, acc.w);
        }
        *(float4*)(obase + (size_t)tau * C_) = acc;
    }
}

extern "C" void kernel_launch(void* const* d_in, const int* in_sizes, int n_in,
                              void* d_out, int out_size, void* d_ws, size_t ws_size,
                              hipStream_t stream) {
    const float* q = (const float*)d_in[0];
    const float* k = (const float*)d_in[1];
    const float* v = (const float*)d_in[2];
    float* out = (float*)d_out;
    char* ws = (char*)d_ws;

    // ws layout: [cross 512KB | mv 256KB | idx | wts | part at 2MB (16.8MB) | z at 20MB (fp16)]
    float*   cross = (float*)ws;
    float*   mv    = (float*)(ws + (1 << 20));
    int*     idx   = (int*)(ws + (1 << 20) + (1 << 18));
    float*   wts   = (float*)(ws + (1 << 20) + (1 << 18) + 4096);
    float2*  part  = (float2*)(ws + (2 << 20));
    __half2* z     = (__half2*)(ws + (size_t)(20 << 20));

    size_t zcap = (ws_size > (size_t)(20 << 20)) ? ws_size - (size_t)(20 << 20) : 0;
    int P = 16;
    while (P > 1 && (size_t)P * C_ * L_ * sizeof(__half2) > zcap) P >>= 1;
    // P=8 chunking: z chunk (64MB fp16) stays L3-resident for fft_bc reads;
    // also keeps per-dispatch dur small enough that all kernels profile.
    if (P > 8) P = 8;

    for (int b0 = 0; b0 < B_; b0 += P) {
        dim3 g1(16, 32, P);   // n2 windows x ch groups x batches
        k_phaseA<<<g1, 256, 0, stream>>>(q, k, z, b0);
        dim3 g2(G_, P);
        k_fft_bc<<<g2, 256, 0, stream>>>(z, part, b0);
    }
    dim3 gr(B_, 17);
    k_reduce<<<gr, 256, 0, stream>>>(part, cross);
    k_ifft<<<B_, 256, 0, stream>>>(cross, mv);
    k_topk<<<1, 256, 0, stream>>>(mv, idx, wts);
    k_agg<<<B_ * (C_ / 4), 256, 0, stream>>>(v, idx, wts, out);
}